// Round 2
// baseline (7316.861 us; speedup 1.0000x reference)
//
#include <hip/hip_runtime.h>

#define N_TOK 131072
#define KCB   1024
#define D     256
#define NL    4
#define BT    64      // tokens per block
#define BK    64      // codes per tile (topk)
#define DKC   32      // d-chunk (topk)
#define TOPC  8       // candidates per token

// ---------- numpy pairwise_sum replication (n=256, sum of squares) ----------
__device__ __forceinline__ float np_pw128_sq(const float* a) {
  float r[8];
  #pragma unroll
  for (int j = 0; j < 8; ++j) r[j] = __fmul_rn(a[j], a[j]);
  #pragma unroll
  for (int i = 8; i < 128; i += 8)
    #pragma unroll
    for (int j = 0; j < 8; ++j) r[j] = __fadd_rn(r[j], __fmul_rn(a[i + j], a[i + j]));
  float t01 = __fadd_rn(r[0], r[1]), t23 = __fadd_rn(r[2], r[3]);
  float t45 = __fadd_rn(r[4], r[5]), t67 = __fadd_rn(r[6], r[7]);
  return __fadd_rn(__fadd_rn(t01, t23), __fadd_rn(t45, t67));
}
__device__ __forceinline__ float np_pw256_sq(const float* a) {
  return __fadd_rn(np_pw128_sq(a), np_pw128_sq(a + 128));
}

// ||e_k||^2 per codebook row, numpy-pairwise-exact
__global__ __launch_bounds__(256) void eh2_kernel(const float* __restrict__ cb,
                                                  float* __restrict__ eh) {
  int row = blockIdx.x * 256 + threadIdx.x;
  if (row < NL * KCB) eh[row] = np_pw256_sq(cb + (size_t)row * D);
}

__device__ __forceinline__ void insert8(float (&v)[8], int (&ix)[8], float nv, int ni) {
  if (nv >= v[7]) return;
  v[7] = nv; ix[7] = ni;
  #pragma unroll
  for (int s = 7; s > 0; --s) {
    if (v[s] < v[s - 1]) {
      float t = v[s - 1]; v[s - 1] = v[s]; v[s] = t;
      int   u = ix[s - 1]; ix[s - 1] = ix[s]; ix[s] = u;
    }
  }
}

// Approximate f32 selection: top-8 candidate codes per token (window >> f32 noise + ulp quantization)
template<int LAYER>
__global__ __launch_bounds__(256, 2) void topk_kernel(
    const float* __restrict__ z, const float* __restrict__ cb,
    const int* __restrict__ idxw, const float* __restrict__ eh,
    int* __restrict__ ti)
{
  __shared__ float As[BT][D + 2];
  __shared__ float Bs[DKC][BK + 2];
  __shared__ int hist[(LAYER > 0 ? LAYER : 1)][BT];

  const int tid = threadIdx.x;
  const int tok0 = blockIdx.x * BT;

  if (LAYER > 0 && tid < LAYER * BT) {
    int l = tid / BT, t = tid % BT;
    hist[l][t] = idxw[l * N_TOK + tok0 + t];
  }
  __syncthreads();

  // residual tile via np-exact elementwise chain (selection only needs ~1e-7 accuracy anyway)
  for (int t = 0; t < BT; ++t) {
    float v = z[(size_t)(tok0 + t) * D + tid];
    #pragma unroll
    for (int l = 0; l < LAYER; ++l) {
      float q = cb[((size_t)l * KCB + hist[l][t]) * D + tid];
      float tmp = __fsub_rn(q, v);
      float u = __fadd_rn(v, tmp);
      v = __fsub_rn(v, u);
    }
    As[t][tid] = v;
  }

  const int tx = tid & 15, ty = tid >> 4;
  float topv[4][8];
  int   topi[4][8];
  #pragma unroll
  for (int i = 0; i < 4; ++i)
    #pragma unroll
    for (int e = 0; e < 8; ++e) { topv[i][e] = 1e30f; topi[i][e] = 0x7fffffff; }

  for (int ct = 0; ct < KCB / BK; ++ct) {
    float acc[4][4] = {};
    for (int dk = 0; dk < D / DKC; ++dk) {
      __syncthreads();
      {
        const int kk = tid & 31;
        const int cbase = tid >> 5;
        #pragma unroll
        for (int s = 0; s < 8; ++s) {
          int c = s * 8 + cbase;
          Bs[kk][c] = cb[((size_t)LAYER * KCB + ct * BK + c) * D + dk * DKC + kk];
        }
      }
      __syncthreads();
      #pragma unroll
      for (int kk = 0; kk < DKC; ++kk) {
        float a0 = As[ty * 4 + 0][dk * DKC + kk];
        float a1 = As[ty * 4 + 1][dk * DKC + kk];
        float a2 = As[ty * 4 + 2][dk * DKC + kk];
        float a3 = As[ty * 4 + 3][dk * DKC + kk];
        float b0 = Bs[kk][tx * 4 + 0];
        float b1 = Bs[kk][tx * 4 + 1];
        float b2 = Bs[kk][tx * 4 + 2];
        float b3 = Bs[kk][tx * 4 + 3];
        acc[0][0] += a0 * b0; acc[0][1] += a0 * b1; acc[0][2] += a0 * b2; acc[0][3] += a0 * b3;
        acc[1][0] += a1 * b0; acc[1][1] += a1 * b1; acc[1][2] += a1 * b2; acc[1][3] += a1 * b3;
        acc[2][0] += a2 * b0; acc[2][1] += a2 * b1; acc[2][2] += a2 * b2; acc[2][3] += a2 * b3;
        acc[3][0] += a3 * b0; acc[3][1] += a3 * b1; acc[3][2] += a3 * b2; acc[3][3] += a3 * b3;
      }
    }
    #pragma unroll
    for (int j = 0; j < 4; ++j) {
      int code = ct * BK + tx * 4 + j;
      float h = eh[LAYER * KCB + code];
      #pragma unroll
      for (int i = 0; i < 4; ++i) {
        float sv = h - 2.f * acc[i][j];
        insert8(topv[i], topi[i], sv, code);
      }
    }
  }

  #pragma unroll
  for (int m = 1; m <= 8; m <<= 1) {
    #pragma unroll
    for (int i = 0; i < 4; ++i) {
      float ov[8]; int oi[8];
      #pragma unroll
      for (int e = 0; e < 8; ++e) {
        ov[e] = __shfl_xor(topv[i][e], m);
        oi[e] = __shfl_xor(topi[i][e], m);
      }
      #pragma unroll
      for (int e = 0; e < 8; ++e) insert8(topv[i], topi[i], ov[e], oi[e]);
    }
  }
  if (tx == 0) {
    #pragma unroll
    for (int i = 0; i < 4; ++i) {
      int tok = tok0 + ty * 4 + i;
      #pragma unroll
      for (int e = 0; e < 8; ++e) ti[tok * TOPC + e] = topi[i][e];
    }
  }
}

// numpy-f32-bitwise rescoring of the 8 candidates; picks np's argmin (first-min ties).
template<int LAYER, bool FINAL>
__global__ __launch_bounds__(256) void refine_np_kernel(
    const float* __restrict__ z, const float* __restrict__ cb,
    const float* __restrict__ eh, const int* __restrict__ ti,
    int* __restrict__ idxw, double* __restrict__ lossB,
    float* __restrict__ out_idx, float* __restrict__ out_q)
{
  __shared__ float rs[BT][D + 1];
  __shared__ float a_sh[BT];
  __shared__ int hist4[NL][BT];
  __shared__ double red[4];

  const int tid = threadIdx.x;
  const int tok0 = blockIdx.x * BT;

  if (LAYER > 0 && tid < LAYER * BT) {
    int l = tid / BT, t = tid % BT;
    hist4[l][t] = idxw[l * N_TOK + tok0 + t];
  }
  __syncthreads();

  // phase 1: residual via numpy's exact elementwise chain r -= (r + (q - r))
  for (int t = 0; t < BT; ++t) {
    float v = z[(size_t)(tok0 + t) * D + tid];
    #pragma unroll
    for (int l = 0; l < LAYER; ++l) {
      float q = cb[((size_t)l * KCB + hist4[l][t]) * D + tid];
      float tmp = __fsub_rn(q, v);
      float u = __fadd_rn(v, tmp);
      v = __fsub_rn(v, u);
    }
    rs[t][tid] = v;
  }
  __syncthreads();

  // phase 2: a_t = numpy pairwise sum of r^2 (bitwise)
  if (tid < BT) a_sh[tid] = np_pw256_sq(&rs[tid][0]);
  __syncthreads();

  // phase 3: per (token, candidate): m = sequential-FMA dot, dist = fl(fl(a+b) - 2m)
  const int w = tid >> 6, lane = tid & 63;
  const int c = lane & 7;
  #pragma unroll
  for (int p = 0; p < 2; ++p) {
    const int tl = p * 32 + w * 8 + (lane >> 3);
    const int tok = tok0 + tl;
    const int cand = ti[tok * TOPC + c];
    const float* er = cb + ((size_t)LAYER * KCB + cand) * D;
    const float* rr = &rs[tl][0];
    float acc = 0.f;
    #pragma unroll 8
    for (int k = 0; k < D; ++k) acc = __fmaf_rn(rr[k], er[k], acc);
    float t1 = __fadd_rn(a_sh[tl], eh[LAYER * KCB + cand]);
    float dist = __fsub_rn(t1, __fmul_rn(2.0f, acc));
    float bd = dist; int bi = cand;
    #pragma unroll
    for (int m = 1; m <= 4; m <<= 1) {
      float od = __shfl_xor(bd, m);
      int   oi = __shfl_xor(bi, m);
      if (od < bd || (od == bd && oi < bi)) { bd = od; bi = oi; }
    }
    if (c == 0) {
      hist4[LAYER][tl] = bi;
      idxw[LAYER * N_TOK + tok] = bi;
      out_idx[(size_t)LAYER * N_TOK + tok] = (float)bi;
    }
  }

  if constexpr (FINAL) {
    __syncthreads();
    // phase 4: full 4-layer replay for q_sum (np-f32 chain) + loss (f64, loose threshold)
    double lacc = 0.0;
    for (int t = 0; t < BT; ++t) {
      float v = z[(size_t)(tok0 + t) * D + tid];
      float qs = 0.f;
      #pragma unroll
      for (int l = 0; l < NL; ++l) {
        float q = cb[((size_t)l * KCB + hist4[l][t]) * D + tid];
        float tmp = __fsub_rn(q, v);
        lacc += (double)tmp * (double)tmp;
        float u = __fadd_rn(v, tmp);
        qs = __fadd_rn(qs, u);
        v = __fsub_rn(v, u);
      }
      out_q[(size_t)(tok0 + t) * D + tid] = qs;
    }
    #pragma unroll
    for (int m = 32; m; m >>= 1) lacc += __shfl_xor(lacc, m);
    if (lane == 0) red[w] = lacc;
    __syncthreads();
    if (tid == 0) lossB[blockIdx.x] = red[0] + red[1] + red[2] + red[3];
  }
}

__global__ __launch_bounds__(256) void finalize_np(const double* __restrict__ lossB,
                                                   float* __restrict__ out0) {
  __shared__ double red[4];
  double s = 0.0;
  for (int i = threadIdx.x; i < N_TOK / BT; i += 256) s += lossB[i];
  #pragma unroll
  for (int m = 32; m; m >>= 1) s += __shfl_xor(s, m);
  const int w = threadIdx.x >> 6, lane = threadIdx.x & 63;
  if (lane == 0) red[w] = s;
  __syncthreads();
  if (threadIdx.x == 0) {
    double t = red[0] + red[1] + red[2] + red[3];
    out0[0] = (float)(1.25 * t / ((double)N_TOK * (double)D));
  }
}

extern "C" void kernel_launch(void* const* d_in, const int* in_sizes, int n_in,
                              void* d_out, int out_size, void* d_ws, size_t ws_size,
                              hipStream_t stream)
{
  (void)in_sizes; (void)n_in; (void)out_size; (void)ws_size;
  const float* z  = (const float*)d_in[0];
  const float* cb = (const float*)d_in[1];
  float* out = (float*)d_out;

  // ws layout (disjoint, ~7.4 MB):
  float*  eh    = (float*)d_ws;                                   // 16 KB
  int*    idxw  = (int*)  ((char*)d_ws + (1 << 16));              // 2 MB  [4][N]
  int*    ti    = (int*)  ((char*)d_ws + (1 << 16) + (1 << 21));  // 4 MB  [N][8]
  double* lossB = (double*)((char*)d_ws + (7 << 20));             // 16 KB [2048]

  float* out_q   = out + 1;                      // [N, 256]
  float* out_idx = out + 1 + (size_t)N_TOK * D;  // [4, N]

  eh2_kernel<<<dim3(16), dim3(256), 0, stream>>>(cb, eh);

  topk_kernel<0><<<dim3(N_TOK / BT), dim3(256), 0, stream>>>(z, cb, idxw, eh, ti);
  refine_np_kernel<0, false><<<dim3(N_TOK / BT), dim3(256), 0, stream>>>(z, cb, eh, ti, idxw, lossB, out_idx, nullptr);

  topk_kernel<1><<<dim3(N_TOK / BT), dim3(256), 0, stream>>>(z, cb, idxw, eh, ti);
  refine_np_kernel<1, false><<<dim3(N_TOK / BT), dim3(256), 0, stream>>>(z, cb, eh, ti, idxw, lossB, out_idx, nullptr);

  topk_kernel<2><<<dim3(N_TOK / BT), dim3(256), 0, stream>>>(z, cb, idxw, eh, ti);
  refine_np_kernel<2, false><<<dim3(N_TOK / BT), dim3(256), 0, stream>>>(z, cb, eh, ti, idxw, lossB, out_idx, nullptr);

  topk_kernel<3><<<dim3(N_TOK / BT), dim3(256), 0, stream>>>(z, cb, idxw, eh, ti);
  refine_np_kernel<3, true><<<dim3(N_TOK / BT), dim3(256), 0, stream>>>(z, cb, eh, ti, idxw, lossB, out_idx, out_q);

  finalize_np<<<dim3(1), dim3(256), 0, stream>>>(lossB, out);
}

// Round 3
// 2846.460 us; speedup vs baseline: 2.5705x; 2.5705x over previous
//
#include <hip/hip_runtime.h>

#define N_TOK 131072
#define KCB   1024
#define D     256
#define NL    4
#define BT    64      // refine/final tokens per block
#define BTK   128     // topk tokens per block
#define BCH   64      // codes per chunk in topk
#define DELTA3 4e-4f

typedef _Float16 halfx8 __attribute__((ext_vector_type(8)));
typedef _Float16 halfx4 __attribute__((ext_vector_type(4)));
typedef float    floatx4 __attribute__((ext_vector_type(4)));

// ---------- numpy pairwise_sum replication (n=256, sum of squares) ----------
__device__ __forceinline__ float np_pw128_sq(const float* a) {
  float r[8];
  #pragma unroll
  for (int j = 0; j < 8; ++j) r[j] = __fmul_rn(a[j], a[j]);
  #pragma unroll
  for (int i = 8; i < 128; i += 8)
    #pragma unroll
    for (int j = 0; j < 8; ++j) r[j] = __fadd_rn(r[j], __fmul_rn(a[i + j], a[i + j]));
  float t01 = __fadd_rn(r[0], r[1]), t23 = __fadd_rn(r[2], r[3]);
  float t45 = __fadd_rn(r[4], r[5]), t67 = __fadd_rn(r[6], r[7]);
  return __fadd_rn(__fadd_rn(t01, t23), __fadd_rn(t45, t67));
}
__device__ __forceinline__ float np_pw256_sq(const float* a) {
  return __fadd_rn(np_pw128_sq(a), np_pw128_sq(a + 128));
}

// ||e_k||^2 per codebook row, numpy-pairwise-exact
__global__ __launch_bounds__(256) void eh2_kernel(const float* __restrict__ cb,
                                                  float* __restrict__ eh) {
  int row = blockIdx.x * 256 + threadIdx.x;
  if (row < NL * KCB) eh[row] = np_pw256_sq(cb + (size_t)row * D);
}

// f32 codebook -> f16 (RNE), linear layout
__global__ __launch_bounds__(256) void cvt_cbh(const float* __restrict__ cb,
                                               _Float16* __restrict__ cbh) {
  int i = (blockIdx.x * 256 + threadIdx.x) * 4;
  float4 v = *(const float4*)(cb + i);
  halfx4 h;
  h[0] = (_Float16)v.x; h[1] = (_Float16)v.y; h[2] = (_Float16)v.z; h[3] = (_Float16)v.w;
  *(halfx4*)(cbh + i) = h;
}

// MFMA f16 selection: per token top-3 values + top-2 indices over 1024 codes.
// np-argmin is provably in {i1,i2} unless (m3-m1) < DELTA3 -> flag for full scan.
template<int LAYER>
__global__ __launch_bounds__(512, 2) void topk_mfma(
    const float* __restrict__ z, const float* __restrict__ cb,
    const _Float16* __restrict__ cbh, const float* __restrict__ eh,
    const int* __restrict__ idxw, int* __restrict__ ti, int* __restrict__ flag)
{
  // XOR-swizzled tiles: 16B block b of row r lives at block-slot (b ^ (r&7)).
  __shared__ __align__(16) _Float16 Ah[BTK * 256];   // 64 KB
  __shared__ __align__(16) _Float16 Bh[BCH * 256];   // 32 KB (reused as merge scratch)
  __shared__ float eh_s[KCB];
  __shared__ int hist[(LAYER > 0 ? LAYER : 1)][BTK];

  const int tid = threadIdx.x;
  const int tok0 = blockIdx.x * BTK;

  if (LAYER > 0) {
    for (int i = tid; i < LAYER * BTK; i += 512) {
      int l = i / BTK, t = i - l * BTK;
      hist[l][t] = idxw[l * N_TOK + tok0 + t];
    }
  }
  for (int i = tid; i < KCB; i += 512) eh_s[i] = eh[LAYER * KCB + i];
  __syncthreads();

  // A build: np-exact f32 residual chain, then f16 RNE, swizzled store
  {
    const int d = tid & 255;
    const int r0 = (tid >> 8) * 64;
    for (int rr = 0; rr < 64; ++rr) {
      int r = r0 + rr;
      float v = z[(size_t)(tok0 + r) * D + d];
      #pragma unroll
      for (int l = 0; l < LAYER; ++l) {
        float q = cb[((size_t)l * KCB + hist[l][r]) * D + d];
        float tmp = __fsub_rn(q, v);
        float u = __fadd_rn(v, tmp);
        v = __fsub_rn(v, u);
      }
      int b = d >> 3;
      int p = b ^ (r & 7);
      Ah[(r * 32 + p) * 8 + (d & 7)] = (_Float16)v;
    }
  }

  const int lane = tid & 63, w = tid >> 6;
  const int rg = w >> 1;   // 0..3 : 32-row group
  const int cg = w & 1;    // 0..1 : 32-col half of chunk
  const int l15 = lane & 15, l4 = lane >> 4;

  float m1[8], m2[8], m3[8]; int i1[8], i2[8];
  #pragma unroll
  for (int s = 0; s < 8; ++s) { m1[s] = m2[s] = m3[s] = 1e30f; i1[s] = i2[s] = 0x7fffffff; }

  const _Float16* srcL = cbh + (size_t)LAYER * KCB * D;

  halfx8 tmp[4];
  // prologue: load + write chunk 0
  #pragma unroll
  for (int i = 0; i < 4; ++i) {
    int e16 = i * 512 + tid;
    int r = e16 >> 5, b = e16 & 31;
    tmp[i] = *(const halfx8*)(srcL + (size_t)r * D + b * 8);
  }
  #pragma unroll
  for (int i = 0; i < 4; ++i) {
    int e16 = i * 512 + tid;
    int r = e16 >> 5, b = e16 & 31;
    int p = b ^ (r & 7);
    *(halfx8*)&Bh[(r * 32 + p) * 8] = tmp[i];
  }
  __syncthreads();

  for (int ct = 0; ct < KCB / BCH; ++ct) {
    if (ct + 1 < KCB / BCH) {
      #pragma unroll
      for (int i = 0; i < 4; ++i) {
        int e16 = i * 512 + tid;
        int r = e16 >> 5, b = e16 & 31;
        tmp[i] = *(const halfx8*)(srcL + (size_t)((ct + 1) * BCH + r) * D + b * 8);
      }
    }
    floatx4 acc[2][2];
    #pragma unroll
    for (int fr = 0; fr < 2; ++fr)
      #pragma unroll
      for (int bf = 0; bf < 2; ++bf)
        #pragma unroll
        for (int e = 0; e < 4; ++e) acc[fr][bf][e] = 0.f;

    #pragma unroll
    for (int ks = 0; ks < 8; ++ks) {
      halfx8 af[2], bv[2];
      #pragma unroll
      for (int fr = 0; fr < 2; ++fr) {
        int r = rg * 32 + fr * 16 + l15;
        int p = (4 * ks + l4) ^ (r & 7);
        af[fr] = *(const halfx8*)&Ah[(r * 32 + p) * 8];
      }
      #pragma unroll
      for (int bf = 0; bf < 2; ++bf) {
        int rb = cg * 32 + bf * 16 + l15;
        int p = (4 * ks + l4) ^ (rb & 7);
        bv[bf] = *(const halfx8*)&Bh[(rb * 32 + p) * 8];
      }
      #pragma unroll
      for (int fr = 0; fr < 2; ++fr)
        #pragma unroll
        for (int bf = 0; bf < 2; ++bf)
          acc[fr][bf] = __builtin_amdgcn_mfma_f32_16x16x32_f16(af[fr], bv[bf], acc[fr][bf], 0, 0, 0);
    }
    // scores + top-3 tracking (score = ||e||^2 - 2 r.e ; ||r||^2 constant per row)
    #pragma unroll
    for (int bf = 0; bf < 2; ++bf) {
      int code = ct * BCH + cg * 32 + bf * 16 + l15;
      float h = eh_s[code];
      #pragma unroll
      for (int fr = 0; fr < 2; ++fr) {
        #pragma unroll
        for (int e = 0; e < 4; ++e) {
          int s4 = fr * 4 + e;
          float s = __builtin_fmaf(acc[fr][bf][e], -2.0f, h);
          bool c1 = s < m1[s4], c2 = s < m2[s4], c3 = s < m3[s4];
          m3[s4] = c2 ? m2[s4] : (c3 ? s : m3[s4]);
          i2[s4] = c1 ? i1[s4] : (c2 ? code : i2[s4]);
          m2[s4] = c1 ? m1[s4] : (c2 ? s : m2[s4]);
          i1[s4] = c1 ? code : i1[s4];
          m1[s4] = c1 ? s : m1[s4];
        }
      }
    }
    __syncthreads();                 // all waves done reading Bh
    if (ct + 1 < KCB / BCH) {
      #pragma unroll
      for (int i = 0; i < 4; ++i) {
        int e16 = i * 512 + tid;
        int r = e16 >> 5, b = e16 & 31;
        int p = b ^ (r & 7);
        *(halfx8*)&Bh[(r * 32 + p) * 8] = tmp[i];
      }
    }
    __syncthreads();                 // Bh ready
  }

  // merge across the 16 lanes sharing each row (lanes l4*16 .. l4*16+15)
  #pragma unroll
  for (int mm = 1; mm <= 8; mm <<= 1) {
    #pragma unroll
    for (int s = 0; s < 8; ++s) {
      float om1 = __shfl_xor(m1[s], mm); int oi1 = __shfl_xor(i1[s], mm);
      float om2 = __shfl_xor(m2[s], mm); int oi2 = __shfl_xor(i2[s], mm);
      float om3 = __shfl_xor(m3[s], mm);
      bool c1 = (om1 < m1[s]) || (om1 == m1[s] && oi1 < i1[s]);
      float w1v = c1 ? om1 : m1[s]; int w1i = c1 ? oi1 : i1[s];
      float l1v = c1 ? m1[s] : om1; int l1i = c1 ? i1[s] : oi1;
      float w2v = c1 ? om2 : m2[s]; int w2i = c1 ? oi2 : i2[s];
      float l2v = c1 ? m2[s] : om2;
      float w3v = c1 ? om3 : m3[s];
      bool c2 = (l1v < w2v) || (l1v == w2v && l1i < w2i);
      float n2v = c2 ? l1v : w2v; int n2i = c2 ? l1i : w2i;
      float n3v = c2 ? fminf(w2v, l2v) : fminf(l1v, w3v);
      m1[s] = w1v; i1[s] = w1i; m2[s] = n2v; i2[s] = n2i; m3[s] = n3v;
    }
  }

  // stash per-wave (rg,cg) results, then combine the two cg halves per row
  float* scr = (float*)Bh;   // [128 rows][2 cg][5]
  if (l15 == 0) {
    #pragma unroll
    for (int s = 0; s < 8; ++s) {
      int row = rg * 32 + (s >> 2) * 16 + l4 * 4 + (s & 3);
      float* pp = scr + (row * 2 + cg) * 5;
      pp[0] = m1[s]; pp[1] = m2[s]; pp[2] = m3[s];
      ((int*)pp)[3] = i1[s]; ((int*)pp)[4] = i2[s];
    }
  }
  __syncthreads();
  if (tid < BTK) {
    const float* pa = scr + (tid * 2 + 0) * 5;
    const float* pb = scr + (tid * 2 + 1) * 5;
    float am1 = pa[0], am2 = pa[1], am3 = pa[2];
    int   ai1 = ((const int*)pa)[3], ai2 = ((const int*)pa)[4];
    float bm1 = pb[0], bm2 = pb[1], bm3 = pb[2];
    int   bi1 = ((const int*)pb)[3], bi2 = ((const int*)pb)[4];
    bool c1 = (bm1 < am1) || (bm1 == am1 && bi1 < ai1);
    float w1v = c1 ? bm1 : am1; int w1i = c1 ? bi1 : ai1;
    float l1v = c1 ? am1 : bm1; int l1i = c1 ? ai1 : bi1;
    float w2v = c1 ? bm2 : am2; int w2i = c1 ? bi2 : ai2;
    float l2v = c1 ? am2 : bm2;
    float w3v = c1 ? bm3 : am3;
    bool c2 = (l1v < w2v) || (l1v == w2v && l1i < w2i);
    int   n2i = c2 ? l1i : w2i;
    float n3v = c2 ? fminf(w2v, l2v) : fminf(l1v, w3v);
    int tok = tok0 + tid;
    ti[tok * 2 + 0] = w1i;
    ti[tok * 2 + 1] = n2i;
    flag[tok] = (n3v - w1v < DELTA3) ? 1 : 0;
  }
}

// np-f32-bitwise rescoring of the 2 candidates; picks np's argmin (first-min ties).
template<int LAYER>
__global__ __launch_bounds__(256) void refine2(
    const float* __restrict__ z, const float* __restrict__ cb,
    const float* __restrict__ eh, const int* __restrict__ ti,
    int* __restrict__ idxw, float* __restrict__ out_idx)
{
  __shared__ float rs[BT][D + 1];
  __shared__ float a_sh[BT];
  __shared__ int histr[(LAYER > 0 ? LAYER : 1)][BT];

  const int tid = threadIdx.x;
  const int tok0 = blockIdx.x * BT;

  if (LAYER > 0 && tid < LAYER * BT) {
    int l = tid / BT, t = tid % BT;
    histr[l][t] = idxw[l * N_TOK + tok0 + t];
  }
  __syncthreads();

  for (int t = 0; t < BT; ++t) {
    float v = z[(size_t)(tok0 + t) * D + tid];
    #pragma unroll
    for (int l = 0; l < LAYER; ++l) {
      float q = cb[((size_t)l * KCB + histr[l][t]) * D + tid];
      float tmp = __fsub_rn(q, v);
      float u = __fadd_rn(v, tmp);
      v = __fsub_rn(v, u);
    }
    rs[t][tid] = v;
  }
  __syncthreads();
  if (tid < BT) a_sh[tid] = np_pw256_sq(&rs[tid][0]);
  __syncthreads();

  const int w = tid >> 6, lane = tid & 63;
  const int c = lane & 1;
  const int tl = w * 16 + ((lane >> 1) & 15);
  const int tok = tok0 + tl;
  const int cand = ti[tok * 2 + c];
  const float* er = cb + ((size_t)LAYER * KCB + cand) * D;
  const float* rr = &rs[tl][0];
  float acc = 0.f;
  #pragma unroll 8
  for (int k = 0; k < D; ++k) acc = __fmaf_rn(rr[k], er[k], acc);
  float t1 = __fadd_rn(a_sh[tl], eh[LAYER * KCB + cand]);
  float dist = __fsub_rn(t1, __fmul_rn(2.0f, acc));
  float od = __shfl_xor(dist, 1);
  int   oi = __shfl_xor(cand, 1);
  int best = ((od < dist) || (od == dist && oi < cand)) ? oi : cand;
  if ((lane & 1) == 0 && lane < 32) {
    idxw[LAYER * N_TOK + tok] = best;
    out_idx[(size_t)LAYER * N_TOK + tok] = (float)best;
  }
}

// Full np-exact 1024-code scan for flagged tokens (rare)
template<int LAYER>
__global__ __launch_bounds__(256) void fallback_scan(
    const float* __restrict__ z, const float* __restrict__ cb,
    const float* __restrict__ eh, const int* __restrict__ flag,
    int* __restrict__ idxw, float* __restrict__ out_idx)
{
  __shared__ float rs[4][D];
  const int w = threadIdx.x >> 6, lane = threadIdx.x & 63;
  const int tbase = blockIdx.x * 64 + w * 16;
  for (int it = 0; it < 16; ++it) {
    const int tok = tbase + it;
    if (!flag[tok]) continue;
    #pragma unroll
    for (int q = 0; q < 4; ++q) {
      int d = lane + 64 * q;
      float v = z[(size_t)tok * D + d];
      #pragma unroll
      for (int l = 0; l < LAYER; ++l) {
        int id = idxw[l * N_TOK + tok];
        float qq = cb[((size_t)l * KCB + id) * D + d];
        float tmp = __fsub_rn(qq, v);
        float u = __fadd_rn(v, tmp);
        v = __fsub_rn(v, u);
      }
      rs[w][d] = v;
    }
    asm volatile("s_waitcnt lgkmcnt(0)" ::: "memory");
    __builtin_amdgcn_sched_barrier(0);
    float a = np_pw256_sq(&rs[w][0]);
    float bd = 1e30f; int bi = 0x7fffffff;
    for (int itc = 0; itc < 16; ++itc) {
      int code = itc * 64 + lane;
      const float* er = cb + ((size_t)LAYER * KCB + code) * D;
      float acc = 0.f;
      #pragma unroll 8
      for (int k = 0; k < D; ++k) acc = __fmaf_rn(rs[w][k], er[k], acc);
      float t1 = __fadd_rn(a, eh[LAYER * KCB + code]);
      float dist = __fsub_rn(t1, __fmul_rn(2.0f, acc));
      if (dist < bd || (dist == bd && code < bi)) { bd = dist; bi = code; }
    }
    #pragma unroll
    for (int mm = 1; mm <= 32; mm <<= 1) {
      float od = __shfl_xor(bd, mm); int oi = __shfl_xor(bi, mm);
      if (od < bd || (od == bd && oi < bi)) { bd = od; bi = oi; }
    }
    if (lane == 0) {
      idxw[LAYER * N_TOK + tok] = bi;
      out_idx[(size_t)LAYER * N_TOK + tok] = (float)bi;
    }
  }
}

// Full 4-layer np-f32 replay: q_sum + loss partials
__global__ __launch_bounds__(256) void final_replay(
    const float* __restrict__ z, const float* __restrict__ cb,
    const int* __restrict__ idxw, double* __restrict__ lossB,
    float* __restrict__ out_q)
{
  __shared__ int hist4[NL][BT];
  __shared__ double red[4];
  const int tid = threadIdx.x;
  const int tok0 = blockIdx.x * BT;
  { int l = tid >> 6, t = tid & 63; hist4[l][t] = idxw[l * N_TOK + tok0 + t]; }
  __syncthreads();
  double lacc = 0.0;
  for (int t = 0; t < BT; ++t) {
    float v = z[(size_t)(tok0 + t) * D + tid];
    float qs = 0.f;
    #pragma unroll
    for (int l = 0; l < NL; ++l) {
      float q = cb[((size_t)l * KCB + hist4[l][t]) * D + tid];
      float tmp = __fsub_rn(q, v);
      lacc += (double)tmp * (double)tmp;
      float u = __fadd_rn(v, tmp);
      qs = __fadd_rn(qs, u);
      v = __fsub_rn(v, u);
    }
    out_q[(size_t)(tok0 + t) * D + tid] = qs;
  }
  const int w = tid >> 6, lane = tid & 63;
  #pragma unroll
  for (int m = 32; m; m >>= 1) lacc += __shfl_xor(lacc, m);
  if (lane == 0) red[w] = lacc;
  __syncthreads();
  if (tid == 0) lossB[blockIdx.x] = red[0] + red[1] + red[2] + red[3];
}

__global__ __launch_bounds__(256) void finalize_np(const double* __restrict__ lossB,
                                                   float* __restrict__ out0) {
  __shared__ double red[4];
  double s = 0.0;
  for (int i = threadIdx.x; i < N_TOK / BT; i += 256) s += lossB[i];
  #pragma unroll
  for (int m = 32; m; m >>= 1) s += __shfl_xor(s, m);
  const int w = threadIdx.x >> 6, lane = threadIdx.x & 63;
  if (lane == 0) red[w] = s;
  __syncthreads();
  if (threadIdx.x == 0) {
    double t = red[0] + red[1] + red[2] + red[3];
    out0[0] = (float)(1.25 * t / ((double)N_TOK * (double)D));
  }
}

extern "C" void kernel_launch(void* const* d_in, const int* in_sizes, int n_in,
                              void* d_out, int out_size, void* d_ws, size_t ws_size,
                              hipStream_t stream)
{
  (void)in_sizes; (void)n_in; (void)out_size; (void)ws_size;
  const float* z  = (const float*)d_in[0];
  const float* cb = (const float*)d_in[1];
  float* out = (float*)d_out;

  // ws layout (disjoint, ~7.7 MB)
  float*    eh    = (float*)d_ws;                          // 16 KB
  _Float16* cbh   = (_Float16*)((char*)d_ws + 0x10000);    // 2 MB f16 codebook
  int*      idxw  = (int*)((char*)d_ws + 0x400000);        // 2 MB [4][N]
  int*      ti    = (int*)((char*)d_ws + 0x600000);        // 1 MB [N][2]
  int*      flag  = (int*)((char*)d_ws + 0x700000);        // 512 KB [N]
  double*   lossB = (double*)((char*)d_ws + 0x780000);     // 16 KB [2048]

  float* out_q   = out + 1;                      // [N, 256]
  float* out_idx = out + 1 + (size_t)N_TOK * D;  // [4, N]

  cvt_cbh<<<dim3(1024), dim3(256), 0, stream>>>(cb, cbh);
  eh2_kernel<<<dim3(16), dim3(256), 0, stream>>>(cb, eh);

  topk_mfma<0><<<dim3(N_TOK / BTK), dim3(512), 0, stream>>>(z, cb, cbh, eh, idxw, ti, flag);
  refine2<0><<<dim3(N_TOK / BT), dim3(256), 0, stream>>>(z, cb, eh, ti, idxw, out_idx);
  fallback_scan<0><<<dim3(2048), dim3(256), 0, stream>>>(z, cb, eh, flag, idxw, out_idx);

  topk_mfma<1><<<dim3(N_TOK / BTK), dim3(512), 0, stream>>>(z, cb, cbh, eh, idxw, ti, flag);
  refine2<1><<<dim3(N_TOK / BT), dim3(256), 0, stream>>>(z, cb, eh, ti, idxw, out_idx);
  fallback_scan<1><<<dim3(2048), dim3(256), 0, stream>>>(z, cb, eh, flag, idxw, out_idx);

  topk_mfma<2><<<dim3(N_TOK / BTK), dim3(512), 0, stream>>>(z, cb, cbh, eh, idxw, ti, flag);
  refine2<2><<<dim3(N_TOK / BT), dim3(256), 0, stream>>>(z, cb, eh, ti, idxw, out_idx);
  fallback_scan<2><<<dim3(2048), dim3(256), 0, stream>>>(z, cb, eh, flag, idxw, out_idx);

  topk_mfma<3><<<dim3(N_TOK / BTK), dim3(512), 0, stream>>>(z, cb, cbh, eh, idxw, ti, flag);
  refine2<3><<<dim3(N_TOK / BT), dim3(256), 0, stream>>>(z, cb, eh, ti, idxw, out_idx);
  fallback_scan<3><<<dim3(2048), dim3(256), 0, stream>>>(z, cb, eh, flag, idxw, out_idx);

  final_replay<<<dim3(N_TOK / BT), dim3(256), 0, stream>>>(z, cb, idxw, lossB, out_q);
  finalize_np<<<dim3(1), dim3(256), 0, stream>>>(lossB, out);
}

// Round 4
// 1501.068 us; speedup vs baseline: 4.8744x; 1.8963x over previous
//
#include <hip/hip_runtime.h>

#define N_TOK 131072
#define KCB   1024
#define D     256
#define NL    4
#define BT    64      // tokens per batch (pair/final kernels)
#define BTK   128     // topk tokens per block
#define BCH   64      // codes per chunk in topk
#define DELTA2 3e-4f
#define DELTA3 4e-4f

typedef _Float16 halfx8 __attribute__((ext_vector_type(8)));
typedef _Float16 halfx4 __attribute__((ext_vector_type(4)));
typedef float    floatx4 __attribute__((ext_vector_type(4)));

// ---------- numpy pairwise_sum replication (n=256, sum of squares) ----------
__device__ __forceinline__ float np_pw128_sq(const float* a) {
  float r[8];
  #pragma unroll
  for (int j = 0; j < 8; ++j) r[j] = __fmul_rn(a[j], a[j]);
  #pragma unroll
  for (int i = 8; i < 128; i += 8)
    #pragma unroll
    for (int j = 0; j < 8; ++j) r[j] = __fadd_rn(r[j], __fmul_rn(a[i + j], a[i + j]));
  float t01 = __fadd_rn(r[0], r[1]), t23 = __fadd_rn(r[2], r[3]);
  float t45 = __fadd_rn(r[4], r[5]), t67 = __fadd_rn(r[6], r[7]);
  return __fadd_rn(__fadd_rn(t01, t23), __fadd_rn(t45, t67));
}
__device__ __forceinline__ float np_pw256_sq(const float* a) {
  return __fadd_rn(np_pw128_sq(a), np_pw128_sq(a + 128));
}

__global__ void zero_cnt(int* cnt) { if (threadIdx.x < 8) cnt[threadIdx.x] = 0; }

// ||e_k||^2 per codebook row, numpy-pairwise-exact
__global__ __launch_bounds__(256) void eh2_kernel(const float* __restrict__ cb,
                                                  float* __restrict__ eh) {
  int row = blockIdx.x * 256 + threadIdx.x;
  if (row < NL * KCB) eh[row] = np_pw256_sq(cb + (size_t)row * D);
}

// f32 codebook -> f16 (RNE), linear layout
__global__ __launch_bounds__(256) void cvt_cbh(const float* __restrict__ cb,
                                               _Float16* __restrict__ cbh) {
  int i = (blockIdx.x * 256 + threadIdx.x) * 4;
  float4 v = *(const float4*)(cb + i);
  halfx4 h;
  h[0] = (_Float16)v.x; h[1] = (_Float16)v.y; h[2] = (_Float16)v.z; h[3] = (_Float16)v.w;
  *(halfx4*)(cbh + i) = h;
}

// codebook transpose: cbT[l][k][code] (f32) for coalesced full-scan gathers
__global__ __launch_bounds__(256) void transpose_cb(const float* __restrict__ cb,
                                                    float* __restrict__ cbT) {
  __shared__ float ts[64][257];
  const int tid = threadIdx.x;
  const int l = blockIdx.x >> 4;
  const int c0 = (blockIdx.x & 15) * 64;
  const float* src = cb + ((size_t)l * KCB + c0) * D;
  for (int r = 0; r < 64; ++r) ts[r][tid] = src[r * D + tid];
  __syncthreads();
  float* dst = cbT + (size_t)l * (KCB * D);
  for (int kk = 0; kk < 64; ++kk) {
    int k = kk * 4 + (tid >> 6);
    int c = tid & 63;
    dst[k * KCB + c0 + c] = ts[c][k];
  }
}

// MFMA f16 selection: top-3 values + top-2 indices per token over 1024 codes.
// Writes i1 as the answer; flags uncertain tokens into compacted lists.
template<int LAYER>
__global__ __launch_bounds__(512, 2) void topk_mfma(
    const float* __restrict__ z, const float* __restrict__ cb,
    const _Float16* __restrict__ cbh, const float* __restrict__ eh,
    int* __restrict__ idxw, int* __restrict__ ti,
    int* __restrict__ listF, int* __restrict__ listP, int* __restrict__ cntA,
    float* __restrict__ out_idx)
{
  // XOR-swizzled tiles: 16B block b of row r lives at block-slot (b ^ (r&7)).
  __shared__ __align__(16) _Float16 Ah[BTK * 256];   // 64 KB
  __shared__ __align__(16) _Float16 Bh[BCH * 256];   // 32 KB (reused as merge scratch)
  __shared__ float eh_s[KCB];
  __shared__ int hist[(LAYER > 0 ? LAYER : 1)][BTK];

  const int tid = threadIdx.x;
  const int tok0 = blockIdx.x * BTK;

  if (LAYER > 0) {
    for (int i = tid; i < LAYER * BTK; i += 512) {
      int l = i / BTK, t = i - l * BTK;
      hist[l][t] = idxw[l * N_TOK + tok0 + t];
    }
  }
  for (int i = tid; i < KCB; i += 512) eh_s[i] = eh[LAYER * KCB + i];
  __syncthreads();

  // A build: np-exact f32 residual chain, then f16 RNE, swizzled store
  {
    const int d = tid & 255;
    const int r0 = (tid >> 8) * 64;
    for (int rr = 0; rr < 64; ++rr) {
      int r = r0 + rr;
      float v = z[(size_t)(tok0 + r) * D + d];
      #pragma unroll
      for (int l = 0; l < LAYER; ++l) {
        float q = cb[((size_t)l * KCB + hist[l][r]) * D + d];
        float tmp = __fsub_rn(q, v);
        float u = __fadd_rn(v, tmp);
        v = __fsub_rn(v, u);
      }
      int b = d >> 3;
      int p = b ^ (r & 7);
      Ah[(r * 32 + p) * 8 + (d & 7)] = (_Float16)v;
    }
  }

  const int lane = tid & 63, w = tid >> 6;
  const int rg = w >> 1;   // 0..3 : 32-row group
  const int cg = w & 1;    // 0..1 : 32-col half of chunk
  const int l15 = lane & 15, l4 = lane >> 4;

  float m1[8], m2[8], m3[8]; int i1[8], i2[8];
  #pragma unroll
  for (int s = 0; s < 8; ++s) { m1[s] = m2[s] = m3[s] = 1e30f; i1[s] = i2[s] = 0x7fffffff; }

  const _Float16* srcL = cbh + (size_t)LAYER * KCB * D;

  halfx8 tmp[4];
  #pragma unroll
  for (int i = 0; i < 4; ++i) {
    int e16 = i * 512 + tid;
    int r = e16 >> 5, b = e16 & 31;
    tmp[i] = *(const halfx8*)(srcL + (size_t)r * D + b * 8);
  }
  #pragma unroll
  for (int i = 0; i < 4; ++i) {
    int e16 = i * 512 + tid;
    int r = e16 >> 5, b = e16 & 31;
    int p = b ^ (r & 7);
    *(halfx8*)&Bh[(r * 32 + p) * 8] = tmp[i];
  }
  __syncthreads();

  for (int ct = 0; ct < KCB / BCH; ++ct) {
    if (ct + 1 < KCB / BCH) {
      #pragma unroll
      for (int i = 0; i < 4; ++i) {
        int e16 = i * 512 + tid;
        int r = e16 >> 5, b = e16 & 31;
        tmp[i] = *(const halfx8*)(srcL + (size_t)((ct + 1) * BCH + r) * D + b * 8);
      }
    }
    floatx4 acc[2][2];
    #pragma unroll
    for (int fr = 0; fr < 2; ++fr)
      #pragma unroll
      for (int bf = 0; bf < 2; ++bf)
        #pragma unroll
        for (int e = 0; e < 4; ++e) acc[fr][bf][e] = 0.f;

    #pragma unroll
    for (int ks = 0; ks < 8; ++ks) {
      halfx8 af[2], bv[2];
      #pragma unroll
      for (int fr = 0; fr < 2; ++fr) {
        int r = rg * 32 + fr * 16 + l15;
        int p = (4 * ks + l4) ^ (r & 7);
        af[fr] = *(const halfx8*)&Ah[(r * 32 + p) * 8];
      }
      #pragma unroll
      for (int bf = 0; bf < 2; ++bf) {
        int rb = cg * 32 + bf * 16 + l15;
        int p = (4 * ks + l4) ^ (rb & 7);
        bv[bf] = *(const halfx8*)&Bh[(rb * 32 + p) * 8];
      }
      #pragma unroll
      for (int fr = 0; fr < 2; ++fr)
        #pragma unroll
        for (int bf = 0; bf < 2; ++bf)
          acc[fr][bf] = __builtin_amdgcn_mfma_f32_16x16x32_f16(af[fr], bv[bf], acc[fr][bf], 0, 0, 0);
    }
    #pragma unroll
    for (int bf = 0; bf < 2; ++bf) {
      int code = ct * BCH + cg * 32 + bf * 16 + l15;
      float h = eh_s[code];
      #pragma unroll
      for (int fr = 0; fr < 2; ++fr) {
        #pragma unroll
        for (int e = 0; e < 4; ++e) {
          int s4 = fr * 4 + e;
          float s = __builtin_fmaf(acc[fr][bf][e], -2.0f, h);
          bool c1 = s < m1[s4], c2 = s < m2[s4], c3 = s < m3[s4];
          m3[s4] = c2 ? m2[s4] : (c3 ? s : m3[s4]);
          i2[s4] = c1 ? i1[s4] : (c2 ? code : i2[s4]);
          m2[s4] = c1 ? m1[s4] : (c2 ? s : m2[s4]);
          i1[s4] = c1 ? code : i1[s4];
          m1[s4] = c1 ? s : m1[s4];
        }
      }
    }
    __syncthreads();
    if (ct + 1 < KCB / BCH) {
      #pragma unroll
      for (int i = 0; i < 4; ++i) {
        int e16 = i * 512 + tid;
        int r = e16 >> 5, b = e16 & 31;
        int p = b ^ (r & 7);
        *(halfx8*)&Bh[(r * 32 + p) * 8] = tmp[i];
      }
    }
    __syncthreads();
  }

  // merge across the 16 lanes sharing each row
  #pragma unroll
  for (int mm = 1; mm <= 8; mm <<= 1) {
    #pragma unroll
    for (int s = 0; s < 8; ++s) {
      float om1 = __shfl_xor(m1[s], mm); int oi1 = __shfl_xor(i1[s], mm);
      float om2 = __shfl_xor(m2[s], mm); int oi2 = __shfl_xor(i2[s], mm);
      float om3 = __shfl_xor(m3[s], mm);
      bool c1 = (om1 < m1[s]) || (om1 == m1[s] && oi1 < i1[s]);
      float w1v = c1 ? om1 : m1[s]; int w1i = c1 ? oi1 : i1[s];
      float l1v = c1 ? m1[s] : om1; int l1i = c1 ? i1[s] : oi1;
      float w2v = c1 ? om2 : m2[s]; int w2i = c1 ? oi2 : i2[s];
      float l2v = c1 ? m2[s] : om2;
      float w3v = c1 ? om3 : m3[s];
      bool c2 = (l1v < w2v) || (l1v == w2v && l1i < w2i);
      float n2v = c2 ? l1v : w2v; int n2i = c2 ? l1i : w2i;
      float n3v = c2 ? fminf(w2v, l2v) : fminf(l1v, w3v);
      m1[s] = w1v; i1[s] = w1i; m2[s] = n2v; i2[s] = n2i; m3[s] = n3v;
    }
  }

  float* scr = (float*)Bh;   // [128 rows][2 cg][5]
  if (l15 == 0) {
    #pragma unroll
    for (int s = 0; s < 8; ++s) {
      int row = rg * 32 + (s >> 2) * 16 + l4 * 4 + (s & 3);
      float* pp = scr + (row * 2 + cg) * 5;
      pp[0] = m1[s]; pp[1] = m2[s]; pp[2] = m3[s];
      ((int*)pp)[3] = i1[s]; ((int*)pp)[4] = i2[s];
    }
  }
  __syncthreads();
  if (tid < BTK) {
    const float* pa = scr + (tid * 2 + 0) * 5;
    const float* pb = scr + (tid * 2 + 1) * 5;
    float am1 = pa[0], am2 = pa[1], am3 = pa[2];
    int   ai1 = ((const int*)pa)[3], ai2 = ((const int*)pa)[4];
    float bm1 = pb[0], bm2 = pb[1], bm3 = pb[2];
    int   bi1 = ((const int*)pb)[3], bi2 = ((const int*)pb)[4];
    bool c1 = (bm1 < am1) || (bm1 == am1 && bi1 < ai1);
    float w1v = c1 ? bm1 : am1; int w1i = c1 ? bi1 : ai1;
    float l1v = c1 ? am1 : bm1; int l1i = c1 ? ai1 : bi1;
    float w2v = c1 ? bm2 : am2; int w2i = c1 ? bi2 : ai2;
    float l2v = c1 ? am2 : bm2;
    float w3v = c1 ? bm3 : am3;
    bool c2 = (l1v < w2v) || (l1v == w2v && l1i < w2i);
    float n2v = c2 ? l1v : w2v;
    int   n2i = c2 ? l1i : w2i;
    float n3v = c2 ? fminf(w2v, l2v) : fminf(l1v, w3v);
    int tok = tok0 + tid;
    idxw[LAYER * N_TOK + tok] = w1i;
    out_idx[(size_t)LAYER * N_TOK + tok] = (float)w1i;
    ti[tok * 2 + 0] = w1i;
    ti[tok * 2 + 1] = n2i;
    if (n3v - w1v < DELTA3) {
      int p = atomicAdd(&cntA[LAYER * 2 + 0], 1);
      listF[p] = tok;
    } else if (n2v - w1v < DELTA2) {
      int p = atomicAdd(&cntA[LAYER * 2 + 1], 1);
      listP[p] = tok;
    }
  }
}

// np-bitwise {i1,i2} comparison for pair-flagged tokens (compacted, batched by 64)
template<int LAYER>
__global__ __launch_bounds__(256) void pair_kernel(
    const float* __restrict__ z, const float* __restrict__ cb,
    const float* __restrict__ eh, const int* __restrict__ ti,
    const int* __restrict__ listP, const int* __restrict__ cntA,
    int* __restrict__ idxw, float* __restrict__ out_idx)
{
  __shared__ float rs[BT][D + 1];
  __shared__ float a_sh[BT];
  __shared__ int toks[BT];
  const int tid = threadIdx.x;
  const int cnt = cntA[LAYER * 2 + 1];
  const int nbat = (cnt + BT - 1) / BT;
  for (int bat = blockIdx.x; bat < nbat; bat += gridDim.x) {
    const int base = bat * BT;
    const int nt = min(BT, cnt - base);
    __syncthreads();
    if (tid < BT) toks[tid] = listP[base + min(tid, nt - 1)];
    __syncthreads();
    for (int i = 0; i < BT; ++i) {
      if (i >= nt) break;
      int token = toks[i];
      float v = z[(size_t)token * D + tid];
      #pragma unroll
      for (int l = 0; l < LAYER; ++l) {
        int id = idxw[l * N_TOK + token];
        float q = cb[((size_t)l * KCB + id) * D + tid];
        float tmp = __fsub_rn(q, v);
        float u = __fadd_rn(v, tmp);
        v = __fsub_rn(v, u);
      }
      rs[i][tid] = v;
    }
    __syncthreads();
    if (tid < nt) a_sh[tid] = np_pw256_sq(&rs[tid][0]);
    __syncthreads();
    const int tl = tid >> 1, c = tid & 1;
    if (tid < 2 * nt) {
      int token = toks[tl];
      int cand = ti[token * 2 + c];
      const float* er = cb + ((size_t)LAYER * KCB + cand) * D;
      const float* rr = &rs[tl][0];
      float acc = 0.f;
      #pragma unroll 8
      for (int k = 0; k < D; ++k) acc = __fmaf_rn(rr[k], er[k], acc);
      float t1 = __fadd_rn(a_sh[tl], eh[LAYER * KCB + cand]);
      float dist = __fsub_rn(t1, __fmul_rn(2.0f, acc));
      float od = __shfl_xor(dist, 1);
      int   oi = __shfl_xor(cand, 1);
      if (c == 0) {
        int best = ((od < dist) || (od == dist && oi < cand)) ? oi : cand;
        idxw[LAYER * N_TOK + token] = best;
        out_idx[(size_t)LAYER * N_TOK + token] = (float)best;
      }
    }
  }
}

// Full np-exact 1024-code scan via transposed codebook; one block per flagged token.
template<int LAYER>
__global__ __launch_bounds__(256) void full_kernel(
    const float* __restrict__ z, const float* __restrict__ cb,
    const float* __restrict__ cbT, const float* __restrict__ eh,
    const int* __restrict__ listF, const int* __restrict__ cntA,
    int* __restrict__ idxw, float* __restrict__ out_idx)
{
  __shared__ float rs[D];
  __shared__ float rv[4]; __shared__ int ri[4];
  const int tid = threadIdx.x;
  const int w = tid >> 6, lane = tid & 63;
  const int cnt = cntA[LAYER * 2 + 0];
  for (int j = blockIdx.x; j < cnt; j += gridDim.x) {
    const int token = listF[j];
    __syncthreads();
    {
      float v = z[(size_t)token * D + tid];
      #pragma unroll
      for (int l = 0; l < LAYER; ++l) {
        int id = idxw[l * N_TOK + token];
        float q = cb[((size_t)l * KCB + id) * D + tid];
        float tmp = __fsub_rn(q, v);
        float u = __fadd_rn(v, tmp);
        v = __fsub_rn(v, u);
      }
      rs[tid] = v;
    }
    __syncthreads();
    float acc[4] = {0.f, 0.f, 0.f, 0.f};
    const float* cT = cbT + (size_t)LAYER * (KCB * D);
    for (int k = 0; k < D; ++k) {
      float r = rs[k];
      #pragma unroll
      for (int jj = 0; jj < 4; ++jj)
        acc[jj] = __fmaf_rn(r, cT[k * KCB + jj * 256 + tid], acc[jj]);
    }
    float a = np_pw256_sq(rs);   // all threads redundantly (LDS broadcast)
    float bd = 1e30f; int bi = 0x7fffffff;
    #pragma unroll
    for (int jj = 0; jj < 4; ++jj) {
      int code = jj * 256 + tid;
      float t1 = __fadd_rn(a, eh[LAYER * KCB + code]);
      float dist = __fsub_rn(t1, __fmul_rn(2.0f, acc[jj]));
      if (dist < bd || (dist == bd && code < bi)) { bd = dist; bi = code; }
    }
    #pragma unroll
    for (int mm = 1; mm <= 32; mm <<= 1) {
      float od = __shfl_xor(bd, mm); int oi = __shfl_xor(bi, mm);
      if (od < bd || (od == bd && oi < bi)) { bd = od; bi = oi; }
    }
    if (lane == 0) { rv[w] = bd; ri[w] = bi; }
    __syncthreads();
    if (tid == 0) {
      float b0 = rv[0]; int i0 = ri[0];
      #pragma unroll
      for (int q = 1; q < 4; ++q)
        if (rv[q] < b0 || (rv[q] == b0 && ri[q] < i0)) { b0 = rv[q]; i0 = ri[q]; }
      idxw[LAYER * N_TOK + token] = i0;
      out_idx[(size_t)LAYER * N_TOK + token] = (float)i0;
    }
  }
}

// Full 4-layer np-f32 replay: q_sum + loss partials
__global__ __launch_bounds__(256) void final_replay(
    const float* __restrict__ z, const float* __restrict__ cb,
    const int* __restrict__ idxw, double* __restrict__ lossB,
    float* __restrict__ out_q)
{
  __shared__ int hist4[NL][BT];
  __shared__ double red[4];
  const int tid = threadIdx.x;
  const int tok0 = blockIdx.x * BT;
  { int l = tid >> 6, t = tid & 63; hist4[l][t] = idxw[l * N_TOK + tok0 + t]; }
  __syncthreads();
  double lacc = 0.0;
  for (int t = 0; t < BT; ++t) {
    float v = z[(size_t)(tok0 + t) * D + tid];
    float qs = 0.f;
    #pragma unroll
    for (int l = 0; l < NL; ++l) {
      float q = cb[((size_t)l * KCB + hist4[l][t]) * D + tid];
      float tmp = __fsub_rn(q, v);
      lacc += (double)tmp * (double)tmp;
      float u = __fadd_rn(v, tmp);
      qs = __fadd_rn(qs, u);
      v = __fsub_rn(v, u);
    }
    out_q[(size_t)(tok0 + t) * D + tid] = qs;
  }
  const int w = tid >> 6, lane = tid & 63;
  #pragma unroll
  for (int m = 32; m; m >>= 1) lacc += __shfl_xor(lacc, m);
  if (lane == 0) red[w] = lacc;
  __syncthreads();
  if (tid == 0) lossB[blockIdx.x] = red[0] + red[1] + red[2] + red[3];
}

__global__ __launch_bounds__(256) void finalize_np(const double* __restrict__ lossB,
                                                   float* __restrict__ out0) {
  __shared__ double red[4];
  double s = 0.0;
  for (int i = threadIdx.x; i < N_TOK / BT; i += 256) s += lossB[i];
  #pragma unroll
  for (int m = 32; m; m >>= 1) s += __shfl_xor(s, m);
  const int w = threadIdx.x >> 6, lane = threadIdx.x & 63;
  if (lane == 0) red[w] = s;
  __syncthreads();
  if (threadIdx.x == 0) {
    double t = red[0] + red[1] + red[2] + red[3];
    out0[0] = (float)(1.25 * t / ((double)N_TOK * (double)D));
  }
}

extern "C" void kernel_launch(void* const* d_in, const int* in_sizes, int n_in,
                              void* d_out, int out_size, void* d_ws, size_t ws_size,
                              hipStream_t stream)
{
  (void)in_sizes; (void)n_in; (void)out_size; (void)ws_size;
  const float* z  = (const float*)d_in[0];
  const float* cb = (const float*)d_in[1];
  float* out = (float*)d_out;

  // ws layout (disjoint, ~11.5 MB)
  float*    eh    = (float*)d_ws;                          // 16 KB
  _Float16* cbh   = (_Float16*)((char*)d_ws + 0x010000);   // 2 MB
  int*      cntA  = (int*)((char*)d_ws + 0x210000);        // 64 B  [4 layers][full,pair]
  int*      listF = (int*)((char*)d_ws + 0x220000);        // 512 KB
  int*      listP = (int*)((char*)d_ws + 0x2A0000);        // 512 KB
  int*      ti    = (int*)((char*)d_ws + 0x320000);        // 1 MB  [N][2]
  int*      idxw  = (int*)((char*)d_ws + 0x420000);        // 2 MB  [4][N]
  double*   lossB = (double*)((char*)d_ws + 0x620000);     // 16 KB
  float*    cbT   = (float*)((char*)d_ws + 0x700000);      // 4 MB  [4][256][1024]

  float* out_q   = out + 1;                      // [N, 256]
  float* out_idx = out + 1 + (size_t)N_TOK * D;  // [4, N]

  zero_cnt<<<dim3(1), dim3(64), 0, stream>>>(cntA);
  cvt_cbh<<<dim3(1024), dim3(256), 0, stream>>>(cb, cbh);
  eh2_kernel<<<dim3(16), dim3(256), 0, stream>>>(cb, eh);
  transpose_cb<<<dim3(64), dim3(256), 0, stream>>>(cb, cbT);

  topk_mfma<0><<<dim3(N_TOK / BTK), dim3(512), 0, stream>>>(z, cb, cbh, eh, idxw, ti, listF, listP, cntA, out_idx);
  pair_kernel<0><<<dim3(64), dim3(256), 0, stream>>>(z, cb, eh, ti, listP, cntA, idxw, out_idx);
  full_kernel<0><<<dim3(128), dim3(256), 0, stream>>>(z, cb, cbT, eh, listF, cntA, idxw, out_idx);

  topk_mfma<1><<<dim3(N_TOK / BTK), dim3(512), 0, stream>>>(z, cb, cbh, eh, idxw, ti, listF, listP, cntA, out_idx);
  pair_kernel<1><<<dim3(64), dim3(256), 0, stream>>>(z, cb, eh, ti, listP, cntA, idxw, out_idx);
  full_kernel<1><<<dim3(128), dim3(256), 0, stream>>>(z, cb, cbT, eh, listF, cntA, idxw, out_idx);

  topk_mfma<2><<<dim3(N_TOK / BTK), dim3(512), 0, stream>>>(z, cb, cbh, eh, idxw, ti, listF, listP, cntA, out_idx);
  pair_kernel<2><<<dim3(64), dim3(256), 0, stream>>>(z, cb, eh, ti, listP, cntA, idxw, out_idx);
  full_kernel<2><<<dim3(128), dim3(256), 0, stream>>>(z, cb, cbT, eh, listF, cntA, idxw, out_idx);

  topk_mfma<3><<<dim3(N_TOK / BTK), dim3(512), 0, stream>>>(z, cb, cbh, eh, idxw, ti, listF, listP, cntA, out_idx);
  pair_kernel<3><<<dim3(64), dim3(256), 0, stream>>>(z, cb, eh, ti, listP, cntA, idxw, out_idx);
  full_kernel<3><<<dim3(128), dim3(256), 0, stream>>>(z, cb, cbT, eh, listF, cntA, idxw, out_idx);

  final_replay<<<dim3(N_TOK / BT), dim3(256), 0, stream>>>(z, cb, idxw, lossB, out_q);
  finalize_np<<<dim3(1), dim3(256), 0, stream>>>(lossB, out);
}